// Round 15
// baseline (329.959 us; speedup 1.0000x reference)
//
#include <hip/hip_runtime.h>
#include <hip/hip_bf16.h>

// ---------------------------------------------------------------------------
// Fused MHA (T5-style rel-bias, mask, softmax) + attn tensor materialization.
// B=4 H=8 S=2048 D=512 Dk=Dv=64.  All matmuls in bf16 MFMA 16x16x32.
// attn_k R13 = R12 with reordered epilogue: ALL 8 waves stream 2 attn rows
// each IMMEDIATELY after recip (pure LDS->nt-store bursts, no VMEM loads ->
// no vmcnt FIFO stalls, 8-wave store concurrency from t=0); PV+oh runs AFTER
// the burst on waves 0-3 (overlaps co-resident block's burst); waves 4-7
// exit early.
// ---------------------------------------------------------------------------

typedef __attribute__((ext_vector_type(8))) short bfrag;   // 8 x bf16 (4 VGPR)
typedef __attribute__((ext_vector_type(4))) float f32x4;
typedef unsigned int u32;

#define MFMA16(a,b,c) __builtin_amdgcn_mfma_f32_16x16x32_bf16(a,b,c,0,0,0)

#define BAR() do{ asm volatile("s_waitcnt lgkmcnt(0)" ::: "memory"); \
                  __builtin_amdgcn_s_barrier(); }while(0)

__device__ __forceinline__ void gl_lds16(const void* g, void* l){
  __builtin_amdgcn_global_load_lds((const __attribute__((address_space(1))) u32*)g,
                                   (__attribute__((address_space(3))) u32*)l, 16, 0, 0);
}
__device__ __forceinline__ short f2bs(float f){   // f32 -> bf16 bits, RNE
  u32 u = __float_as_uint(f);
  u = (u + 0x7fffu + ((u>>16)&1u)) >> 16;
  return (short)u;
}
__device__ __forceinline__ float b2f(short s){
  return __uint_as_float(((u32)(unsigned short)s) << 16);
}
__device__ __forceinline__ u32 pack2(float a, float b){
  float2 t; t.x = a; t.y = b;
  __hip_bfloat162 h = __float22bfloat162_rn(t);   // cvt_pk path
  return *(u32*)&h;
}

#define BB 4
#define HH 8
#define SS 2048
#define DD 512

// workspace byte offsets (total ~58 MB)
#define WQT_OFF  0u
#define WKT_OFF  524288u
#define WVT_OFF  1048576u
#define WFCT_OFF 1572864u
#define QB_OFF   2097152u
#define KB_OFF   10485760u
#define VB_OFF   18874368u
#define QH_OFF   27262976u
#define KH_OFF   35651584u
#define VT_OFF   44040192u
#define OH_OFF   52428800u

// ------------------------- converts --------------------------------------
__global__ __launch_bounds__(256) void conv_w_k(const float* w0,const float* w1,
                                                const float* w2,const float* w3, char* ws){
  const float* w; short* o;
  switch(blockIdx.z){
    case 0:  w=w0; o=(short*)(ws+WQT_OFF); break;
    case 1:  w=w1; o=(short*)(ws+WKT_OFF); break;
    case 2:  w=w2; o=(short*)(ws+WVT_OFF); break;
    default: w=w3; o=(short*)(ws+WFCT_OFF); break;
  }
  int t  = blockIdx.x*256 + threadIdx.x;   // 32768 threads: 512 rows x 64
  int n  = t >> 6;
  int k0 = (t & 63) << 3;
  bfrag v;
  #pragma unroll
  for (int j=0;j<8;++j) v[j] = f2bs(w[(k0+j)*512 + n]);   // Wt[n][k] = W[k][n]
  *(bfrag*)(o + n*512 + k0) = v;
}

__global__ __launch_bounds__(256) void conv_x_k(const float* x0,const float* x1,
                                                const float* x2, char* ws){
  const float* x; short* o;
  switch(blockIdx.z){
    case 0:  x=x0; o=(short*)(ws+QB_OFF); break;
    case 1:  x=x1; o=(short*)(ws+KB_OFF); break;
    default: x=x2; o=(short*)(ws+VB_OFF); break;
  }
  int i = (blockIdx.x*256 + threadIdx.x) << 3;
  float4 a = *(const float4*)(x+i);
  float4 b = *(const float4*)(x+i+4);
  bfrag v;
  v[0]=f2bs(a.x); v[1]=f2bs(a.y); v[2]=f2bs(a.z); v[3]=f2bs(a.w);
  v[4]=f2bs(b.x); v[5]=f2bs(b.y); v[6]=f2bs(b.z); v[7]=f2bs(b.w);
  *(bfrag*)(o+i) = v;
}

// ------------------------- generic bt-GEMM core ---------------------------
__device__ void gemm_core(const short* A, const short* Bt, char* Cout, int mode, int bid){
  __shared__ __align__(16) char lds[32768];
  int i0, j0;
  if (mode==1){ i0 = (bid&3)<<7; j0 = (bid>>2)<<7; }
  else        { i0 = (bid>>2)<<7; j0 = (bid&3)<<7; }
  int tid = threadIdx.x;
  int l = tid & 63, w = tid >> 6;
  int wr = (w>>1)<<6, wc = (w&1)<<6;
  int l15 = l & 15, l4 = l >> 4;
  f32x4 acc[4][4];
  #pragma unroll
  for(int a=0;a<4;++a)
    #pragma unroll
    for(int b=0;b<4;++b) acc[a][b] = (f32x4){0.f,0.f,0.f,0.f};
  const char* Ab = (const char*)A;
  const char* Bb = (const char*)Bt;
  for (int kk=0; kk<8; ++kk){
    #pragma unroll
    for (int it=0; it<4; ++it){
      int ci = it*256 + tid;
      int row = ci>>3, cc = ci&7;
      gl_lds16(Ab + (size_t)(i0+row)*1024 + kk*128 + ((cc^(row&7))<<4),
               lds + ((it*256 + w*64)<<4));
      gl_lds16(Bb + (size_t)(j0+row)*1024 + kk*128 + ((cc^(row&7))<<4),
               lds + 16384 + ((it*256 + w*64)<<4));
    }
    asm volatile("s_waitcnt vmcnt(0)" ::: "memory");
    __syncthreads();
    #pragma unroll
    for (int kb=0; kb<2; ++kb){
      bfrag af[4], bf[4];
      #pragma unroll
      for (int mi=0;mi<4;++mi){
        int row = wr + mi*16 + l15;
        af[mi] = *(const bfrag*)(lds + row*128 + (((kb*4 + l4) ^ (row&7))<<4));
      }
      #pragma unroll
      for (int ni=0;ni<4;++ni){
        int row = wc + ni*16 + l15;
        bf[ni] = *(const bfrag*)(lds + 16384 + row*128 + (((kb*4 + l4) ^ (row&7))<<4));
      }
      #pragma unroll
      for (int mi=0;mi<4;++mi)
        #pragma unroll
        for (int ni=0;ni<4;++ni)
          acc[mi][ni] = MFMA16(af[mi], bf[ni], acc[mi][ni]);
    }
    __syncthreads();
  }
  #pragma unroll
  for (int mi=0;mi<4;++mi){
    #pragma unroll
    for (int ni=0;ni<4;++ni){
      #pragma unroll
      for (int r=0;r<4;++r){
        int i = i0 + wr + mi*16 + (l4<<2) + r;
        int j = j0 + wc + ni*16 + l15;
        float v = acc[mi][ni][r];
        if (mode==2){
          ((float*)Cout)[(size_t)i*512 + j] = v;
        } else if (mode==0){
          size_t o = ((size_t)(((i>>11)<<3) + (j>>6))*2048 + (size_t)(i&2047))*64 + (j&63);
          ((short*)Cout)[o] = f2bs(v);
        } else {
          size_t o = ((size_t)(((j>>11)<<3) + (i>>6))*64 + (size_t)(i&63))*2048 + (j&2047);
          ((short*)Cout)[o] = f2bs(v);
        }
      }
    }
  }
}

__global__ __launch_bounds__(256,2) void gemm_proj_k(char* ws){
  switch(blockIdx.z){
    case 0:  gemm_core((const short*)(ws+QB_OFF),  (const short*)(ws+WQT_OFF), ws+QH_OFF, 0, blockIdx.x); break;
    case 1:  gemm_core((const short*)(ws+KB_OFF),  (const short*)(ws+WKT_OFF), ws+KH_OFF, 0, blockIdx.x); break;
    default: gemm_core((const short*)(ws+WVT_OFF), (const short*)(ws+VB_OFF),  ws+VT_OFF, 1, blockIdx.x); break;
  }
}
__global__ __launch_bounds__(256,2) void gemm_final_k(char* ws, float* out){
  gemm_core((const short*)(ws+OH_OFF), (const short*)(ws+WFCT_OFF), (char*)out, 2, blockIdx.x);
}

// ------------------------- fused attention --------------------------------
// block = 16 q-rows, 8 waves, 2 blocks/CU (74 KB LDS). Swapped-QK layout.
#define MSK_OFF_L   65536
#define BIAS_OFF_L  73728
#define WSUM_OFF_L  73872
#define RECIP_OFF_L 74384
#define LDS_TOTAL   74496

__global__ __launch_bounds__(512,4) void attn_k(char* ws, const int* mask,
                                                const float* rel_bias, float* attn_out){
  extern __shared__ __align__(16) char sm[];
  int tid = threadIdx.x;
  int l = tid & 63, w = tid >> 6;
  int l15 = l & 15, l4 = l >> 4;
  int bh = blockIdx.x, qblk = blockIdx.y;      // bh fast => same-bh blocks share XCD
  int b = bh >> 3, h = bh & 7;
  const short* qhb = (const short*)(ws+QH_OFF) + (size_t)bh*SS*64;
  const char*  khb = ws + KH_OFF + (size_t)bh*SS*128;    // 128 B per kpos row
  const char*  vtb = ws + VT_OFF + (size_t)bh*64*SS*2;   // 4096 B per d row

  // mask -> LDS f32 (0/1), bias row -> LDS
  {
    const int4* m4 = (const int4*)(mask + b*SS);
    int4 ma = m4[tid];
    float4* mf = (float4*)(sm + MSK_OFF_L);
    mf[tid] = make_float4(ma.x?1.f:0.f, ma.y?1.f:0.f, ma.z?1.f:0.f, ma.w?1.f:0.f);
  }
  if (tid < 33) ((float*)(sm+BIAS_OFF_L))[tid] = rel_bias[tid*HH + h];
  float bias0  = rel_bias[h];          // n<=0 tiles
  float bias32 = rel_bias[32*HH + h];  // n>=32 tiles
  const float* biasl = (const float*)(sm+BIAS_OFF_L);
  const float* maskl = (const float*)(sm+MSK_OFF_L);

  // Q fragments (16 rows, both dk halves); qrow = l15 (B-operand col)
  int qrow = (qblk<<4) + l15;
  bfrag qA0 = *(const bfrag*)(qhb + (size_t)qrow*64 + l4*8);
  bfrag qA1 = *(const bfrag*)(qhb + (size_t)qrow*64 + 32 + l4*8);
  int r0 = qblk<<4;
  int wbase = w << 8;                   // this wave's 256-kpos range

  __syncthreads();                      // mask/bias visible

  // ---- Phase A: swapped QK^T + exp + rowsum + p->LDS (b64 writes) ----
  float rs = 0.f;
  #pragma unroll 2
  for (int t=0; t<16; ++t){
    int c0 = wbase + (t<<4);
    const char* kr = khb + (size_t)(c0 + l15)*128 + (l4<<4);
    bfrag b0 = *(const bfrag*)(kr);       // dk 0..31 slice (A-frag)
    bfrag b1 = *(const bfrag*)(kr + 64);  // dk 32..63
    f32x4 acc = (f32x4){0.f,0.f,0.f,0.f};
    acc = MFMA16(b0, qA0, acc);           // SWAPPED: lane -> S[qrow=l15][kp=c0+4*l4+r]
    acc = MFMA16(b1, qA1, acc);
    float4 m4v = *(const float4*)(maskl + c0 + (l4<<2));
    float pr[4];
    if (c0 >= r0+16){                     // all n<=0
      #pragma unroll
      for (int r=0;r<4;++r) pr[r] = __expf(acc[r]*0.125f + bias0);
    } else if (c0 <= r0-47){              // all n>=32
      #pragma unroll
      for (int r=0;r<4;++r) pr[r] = __expf(acc[r]*0.125f + bias32);
    } else {
      #pragma unroll
      for (int r=0;r<4;++r){
        int n = (r0 + l15) - (c0 + (l4<<2) + r);
        n = n<0 ? 0 : (n>32 ? 32 : n);
        pr[r] = __expf(acc[r]*0.125f + biasl[n]);
      }
    }
    float p0 = m4v.x*pr[0], p1 = m4v.y*pr[1], p2 = m4v.z*pr[2], p3 = m4v.w*pr[3];
    rs += (p0+p1)+(p2+p3);
    // p -> LDS [qrow=l15][kp], swizzled 16B chunks, one b64 write
    int byte = (c0 + (l4<<2)) << 1;
    int ch = (byte>>4) ^ l15;
    uint2 pk; pk.x = pack2(p0,p1); pk.y = pack2(p2,p3);
    *(uint2*)(sm + l15*4096 + (ch<<4) + (byte&15)) = pk;
  }

  // ---- row-sum: reduce over l4 groups (2 shfl), then over 8 waves ----
  {
    rs += __shfl_xor(rs, 16);
    rs += __shfl_xor(rs, 32);
    float* wsum = (float*)(sm+WSUM_OFF_L);
    if (l < 16) wsum[(w<<4) + l15] = rs;
  }
  BAR();
  if (tid < 16){
    float* wsum = (float*)(sm+WSUM_OFF_L);
    float t2 = 0.f;
    #pragma unroll
    for (int i=0;i<8;++i) t2 += wsum[(i<<4) + tid];
    ((float*)(sm+RECIP_OFF_L))[tid] = 1.f/t2;
  }
  BAR();
  const float* recip = (const float*)(sm+RECIP_OFF_L);
  float* attb = (float*)(attn_out + (size_t)bh*SS*SS + (size_t)r0*SS);

  // stream one full 8KB attn row: 8 hoisted LDS reads -> 8 independent
  // back-to-back nt stores at consecutive addresses. No VMEM loads inside.
  auto stream_row = [&](int row){
    float rc = recip[row];
    float* dst = attb + (size_t)row*SS;
    uint2 pk[8];
    #pragma unroll
    for (int c=0;c<8;++c){
      int byte = (c<<9) + (l<<3);               // bf16 byte offset in row
      int ch = (byte>>4) ^ row;
      pk[c] = *(const uint2*)(sm + row*4096 + (ch<<4) + (byte&15));
    }
    #pragma unroll
    for (int c=0;c<8;++c){
      short s0 = (short)(pk[c].x & 0xffff), s1 = (short)(pk[c].x >> 16);
      short s2 = (short)(pk[c].y & 0xffff), s3 = (short)(pk[c].y >> 16);
      f32x4 o = (f32x4){ b2f(s0)*rc, b2f(s1)*rc, b2f(s2)*rc, b2f(s3)*rc };
      __builtin_nontemporal_store(o, (f32x4*)(dst + (c<<8) + (l<<2)));
    }
  };

  // ---- STORE BURST FIRST: all 8 waves stream 2 rows each ----
  stream_row(w<<1);
  stream_row((w<<1)+1);

  // ---- PV AFTER the burst (waves 0-3): dv-stripe w*16, full k, oh ----
  if (w < 4){
    f32x4 acco = (f32x4){0.f,0.f,0.f,0.f};
    int dbase = w<<4;
    const char* vr = vtb + (size_t)(dbase + l15)*4096 + (l4<<4);
    #pragma unroll 4
    for (int kt=0; kt<64; ++kt){
      int ch = ((kt<<2) + l4) ^ l15;            // p chunk idx ^ row swizzle
      bfrag af = *(const bfrag*)(sm + l15*4096 + (ch<<4));
      bfrag bv = *(const bfrag*)(vr + (kt<<6));
      acco = MFMA16(af, bv, acco);
    }
    short* oh = (short*)(ws + OH_OFF);
    #pragma unroll
    for (int r=0;r<4;++r){
      int rowl = (l4<<2) + r;
      float rc = recip[rowl];
      size_t sg = (size_t)b*SS + (qblk<<4) + rowl;
      oh[sg*512 + h*64 + dbase + l15] = f2bs(acco[r]*rc);
    }
  }
}

// ------------------------- launch -----------------------------------------
extern "C" void kernel_launch(void* const* d_in, const int* in_sizes, int n_in,
                              void* d_out, int out_size, void* d_ws, size_t ws_size,
                              hipStream_t stream){
  const float* q   = (const float*)d_in[0];
  const float* k   = (const float*)d_in[1];
  const float* v   = (const float*)d_in[2];
  const int*  mask = (const int*)  d_in[3];
  const float* Wq  = (const float*)d_in[4];
  const float* Wk  = (const float*)d_in[5];
  const float* Wv  = (const float*)d_in[6];
  const float* Wfc = (const float*)d_in[7];
  const float* rb  = (const float*)d_in[8];
  char* ws = (char*)d_ws;
  float* out  = (float*)d_out;
  float* attn = out + (size_t)BB*SS*512;

  (void)hipFuncSetAttribute((const void*)attn_k,
        hipFuncAttributeMaxDynamicSharedMemorySize, LDS_TOTAL);

  conv_w_k<<<dim3(128,1,4), 256, 0, stream>>>(Wq, Wk, Wv, Wfc, ws);
  conv_x_k<<<dim3(2048,1,3), 256, 0, stream>>>(q, k, v, ws);
  gemm_proj_k<<<dim3(256,1,3), 256, 0, stream>>>(ws);
  attn_k<<<dim3(32,128), 512, LDS_TOTAL, stream>>>(ws, mask, rb, attn);
  gemm_final_k<<<dim3(256,1,1), 256, 0, stream>>>(ws, out);
}

// Round 16
// 320.002 us; speedup vs baseline: 1.0311x; 1.0311x over previous
//
#include <hip/hip_runtime.h>
#include <hip/hip_bf16.h>

// ---------------------------------------------------------------------------
// Fused MHA (T5-style rel-bias, mask, softmax) + attn tensor materialization.
// B=4 H=8 S=2048 D=512 Dk=Dv=64.  All matmuls in bf16 MFMA 16x16x32.
// attn_k R12 (BEST, 320 us) = swapped-QK phase A -> rowsum -> wave-split:
//  waves 0-3 PV (full k, 16-dv stripe) + oh, then stream 1 attn row each;
//  waves 4-7 stream 3 attn rows each (8 hoisted LDS reads -> 8 independent
//  back-to-back nt f32x4 stores, linear 8KB row runs).
// Empirical plateau: 9 schedule variants converge at ~2.1 TB/s in-kernel
// store acceptance (fillBuffer: 6.6); attn_k ~= 537MB/2.15TB/s ~= 250 us
// + ~60 us serial GEMM DAG => ~310 us floor; this kernel measures 320.
// ---------------------------------------------------------------------------

typedef __attribute__((ext_vector_type(8))) short bfrag;   // 8 x bf16 (4 VGPR)
typedef __attribute__((ext_vector_type(4))) float f32x4;
typedef unsigned int u32;

#define MFMA16(a,b,c) __builtin_amdgcn_mfma_f32_16x16x32_bf16(a,b,c,0,0,0)

#define BAR() do{ asm volatile("s_waitcnt lgkmcnt(0)" ::: "memory"); \
                  __builtin_amdgcn_s_barrier(); }while(0)

__device__ __forceinline__ void gl_lds16(const void* g, void* l){
  __builtin_amdgcn_global_load_lds((const __attribute__((address_space(1))) u32*)g,
                                   (__attribute__((address_space(3))) u32*)l, 16, 0, 0);
}
__device__ __forceinline__ short f2bs(float f){   // f32 -> bf16 bits, RNE
  u32 u = __float_as_uint(f);
  u = (u + 0x7fffu + ((u>>16)&1u)) >> 16;
  return (short)u;
}
__device__ __forceinline__ float b2f(short s){
  return __uint_as_float(((u32)(unsigned short)s) << 16);
}
__device__ __forceinline__ u32 pack2(float a, float b){
  float2 t; t.x = a; t.y = b;
  __hip_bfloat162 h = __float22bfloat162_rn(t);   // cvt_pk path
  return *(u32*)&h;
}

#define BB 4
#define HH 8
#define SS 2048
#define DD 512

// workspace byte offsets (total ~58 MB)
#define WQT_OFF  0u
#define WKT_OFF  524288u
#define WVT_OFF  1048576u
#define WFCT_OFF 1572864u
#define QB_OFF   2097152u
#define KB_OFF   10485760u
#define VB_OFF   18874368u
#define QH_OFF   27262976u
#define KH_OFF   35651584u
#define VT_OFF   44040192u
#define OH_OFF   52428800u

// ------------------------- converts --------------------------------------
__global__ __launch_bounds__(256) void conv_w_k(const float* w0,const float* w1,
                                                const float* w2,const float* w3, char* ws){
  const float* w; short* o;
  switch(blockIdx.z){
    case 0:  w=w0; o=(short*)(ws+WQT_OFF); break;
    case 1:  w=w1; o=(short*)(ws+WKT_OFF); break;
    case 2:  w=w2; o=(short*)(ws+WVT_OFF); break;
    default: w=w3; o=(short*)(ws+WFCT_OFF); break;
  }
  int t  = blockIdx.x*256 + threadIdx.x;   // 32768 threads: 512 rows x 64
  int n  = t >> 6;
  int k0 = (t & 63) << 3;
  bfrag v;
  #pragma unroll
  for (int j=0;j<8;++j) v[j] = f2bs(w[(k0+j)*512 + n]);   // Wt[n][k] = W[k][n]
  *(bfrag*)(o + n*512 + k0) = v;
}

__global__ __launch_bounds__(256) void conv_x_k(const float* x0,const float* x1,
                                                const float* x2, char* ws){
  const float* x; short* o;
  switch(blockIdx.z){
    case 0:  x=x0; o=(short*)(ws+QB_OFF); break;
    case 1:  x=x1; o=(short*)(ws+KB_OFF); break;
    default: x=x2; o=(short*)(ws+VB_OFF); break;
  }
  int i = (blockIdx.x*256 + threadIdx.x) << 3;
  float4 a = *(const float4*)(x+i);
  float4 b = *(const float4*)(x+i+4);
  bfrag v;
  v[0]=f2bs(a.x); v[1]=f2bs(a.y); v[2]=f2bs(a.z); v[3]=f2bs(a.w);
  v[4]=f2bs(b.x); v[5]=f2bs(b.y); v[6]=f2bs(b.z); v[7]=f2bs(b.w);
  *(bfrag*)(o+i) = v;
}

// ------------------------- generic bt-GEMM core ---------------------------
__device__ void gemm_core(const short* A, const short* Bt, char* Cout, int mode, int bid){
  __shared__ __align__(16) char lds[32768];
  int i0, j0;
  if (mode==1){ i0 = (bid&3)<<7; j0 = (bid>>2)<<7; }
  else        { i0 = (bid>>2)<<7; j0 = (bid&3)<<7; }
  int tid = threadIdx.x;
  int l = tid & 63, w = tid >> 6;
  int wr = (w>>1)<<6, wc = (w&1)<<6;
  int l15 = l & 15, l4 = l >> 4;
  f32x4 acc[4][4];
  #pragma unroll
  for(int a=0;a<4;++a)
    #pragma unroll
    for(int b=0;b<4;++b) acc[a][b] = (f32x4){0.f,0.f,0.f,0.f};
  const char* Ab = (const char*)A;
  const char* Bb = (const char*)Bt;
  for (int kk=0; kk<8; ++kk){
    #pragma unroll
    for (int it=0; it<4; ++it){
      int ci = it*256 + tid;
      int row = ci>>3, cc = ci&7;
      gl_lds16(Ab + (size_t)(i0+row)*1024 + kk*128 + ((cc^(row&7))<<4),
               lds + ((it*256 + w*64)<<4));
      gl_lds16(Bb + (size_t)(j0+row)*1024 + kk*128 + ((cc^(row&7))<<4),
               lds + 16384 + ((it*256 + w*64)<<4));
    }
    asm volatile("s_waitcnt vmcnt(0)" ::: "memory");
    __syncthreads();
    #pragma unroll
    for (int kb=0; kb<2; ++kb){
      bfrag af[4], bf[4];
      #pragma unroll
      for (int mi=0;mi<4;++mi){
        int row = wr + mi*16 + l15;
        af[mi] = *(const bfrag*)(lds + row*128 + (((kb*4 + l4) ^ (row&7))<<4));
      }
      #pragma unroll
      for (int ni=0;ni<4;++ni){
        int row = wc + ni*16 + l15;
        bf[ni] = *(const bfrag*)(lds + 16384 + row*128 + (((kb*4 + l4) ^ (row&7))<<4));
      }
      #pragma unroll
      for (int mi=0;mi<4;++mi)
        #pragma unroll
        for (int ni=0;ni<4;++ni)
          acc[mi][ni] = MFMA16(af[mi], bf[ni], acc[mi][ni]);
    }
    __syncthreads();
  }
  #pragma unroll
  for (int mi=0;mi<4;++mi){
    #pragma unroll
    for (int ni=0;ni<4;++ni){
      #pragma unroll
      for (int r=0;r<4;++r){
        int i = i0 + wr + mi*16 + (l4<<2) + r;
        int j = j0 + wc + ni*16 + l15;
        float v = acc[mi][ni][r];
        if (mode==2){
          ((float*)Cout)[(size_t)i*512 + j] = v;
        } else if (mode==0){
          size_t o = ((size_t)(((i>>11)<<3) + (j>>6))*2048 + (size_t)(i&2047))*64 + (j&63);
          ((short*)Cout)[o] = f2bs(v);
        } else {
          size_t o = ((size_t)(((j>>11)<<3) + (i>>6))*64 + (size_t)(i&63))*2048 + (j&2047);
          ((short*)Cout)[o] = f2bs(v);
        }
      }
    }
  }
}

__global__ __launch_bounds__(256,2) void gemm_proj_k(char* ws){
  switch(blockIdx.z){
    case 0:  gemm_core((const short*)(ws+QB_OFF),  (const short*)(ws+WQT_OFF), ws+QH_OFF, 0, blockIdx.x); break;
    case 1:  gemm_core((const short*)(ws+KB_OFF),  (const short*)(ws+WKT_OFF), ws+KH_OFF, 0, blockIdx.x); break;
    default: gemm_core((const short*)(ws+WVT_OFF), (const short*)(ws+VB_OFF),  ws+VT_OFF, 1, blockIdx.x); break;
  }
}
__global__ __launch_bounds__(256,2) void gemm_final_k(char* ws, float* out){
  gemm_core((const short*)(ws+OH_OFF), (const short*)(ws+WFCT_OFF), (char*)out, 2, blockIdx.x);
}

// ------------------------- fused attention --------------------------------
// block = 16 q-rows, 8 waves, 2 blocks/CU (74 KB LDS). Swapped-QK layout.
#define MSK_OFF_L   65536
#define BIAS_OFF_L  73728
#define WSUM_OFF_L  73872
#define RECIP_OFF_L 74384
#define LDS_TOTAL   74496

__global__ __launch_bounds__(512,4) void attn_k(char* ws, const int* mask,
                                                const float* rel_bias, float* attn_out){
  extern __shared__ __align__(16) char sm[];
  int tid = threadIdx.x;
  int l = tid & 63, w = tid >> 6;
  int l15 = l & 15, l4 = l >> 4;
  int bh = blockIdx.x, qblk = blockIdx.y;      // bh fast => same-bh blocks share XCD
  int b = bh >> 3, h = bh & 7;
  const short* qhb = (const short*)(ws+QH_OFF) + (size_t)bh*SS*64;
  const char*  khb = ws + KH_OFF + (size_t)bh*SS*128;    // 128 B per kpos row
  const char*  vtb = ws + VT_OFF + (size_t)bh*64*SS*2;   // 4096 B per d row

  // mask -> LDS f32 (0/1), bias row -> LDS
  {
    const int4* m4 = (const int4*)(mask + b*SS);
    int4 ma = m4[tid];
    float4* mf = (float4*)(sm + MSK_OFF_L);
    mf[tid] = make_float4(ma.x?1.f:0.f, ma.y?1.f:0.f, ma.z?1.f:0.f, ma.w?1.f:0.f);
  }
  if (tid < 33) ((float*)(sm+BIAS_OFF_L))[tid] = rel_bias[tid*HH + h];
  float bias0  = rel_bias[h];          // n<=0 tiles
  float bias32 = rel_bias[32*HH + h];  // n>=32 tiles
  const float* biasl = (const float*)(sm+BIAS_OFF_L);
  const float* maskl = (const float*)(sm+MSK_OFF_L);

  // Q fragments (16 rows, both dk halves); qrow = l15 (B-operand col)
  int qrow = (qblk<<4) + l15;
  bfrag qA0 = *(const bfrag*)(qhb + (size_t)qrow*64 + l4*8);
  bfrag qA1 = *(const bfrag*)(qhb + (size_t)qrow*64 + 32 + l4*8);
  int r0 = qblk<<4;
  int wbase = w << 8;                   // this wave's 256-kpos range

  __syncthreads();                      // mask/bias visible

  // ---- Phase A: swapped QK^T + exp + rowsum + p->LDS (b64 writes) ----
  float rs = 0.f;
  #pragma unroll 2
  for (int t=0; t<16; ++t){
    int c0 = wbase + (t<<4);
    const char* kr = khb + (size_t)(c0 + l15)*128 + (l4<<4);
    bfrag b0 = *(const bfrag*)(kr);       // dk 0..31 slice (A-frag)
    bfrag b1 = *(const bfrag*)(kr + 64);  // dk 32..63
    f32x4 acc = (f32x4){0.f,0.f,0.f,0.f};
    acc = MFMA16(b0, qA0, acc);           // SWAPPED: lane -> S[qrow=l15][kp=c0+4*l4+r]
    acc = MFMA16(b1, qA1, acc);
    float4 m4v = *(const float4*)(maskl + c0 + (l4<<2));
    float pr[4];
    if (c0 >= r0+16){                     // all n<=0
      #pragma unroll
      for (int r=0;r<4;++r) pr[r] = __expf(acc[r]*0.125f + bias0);
    } else if (c0 <= r0-47){              // all n>=32
      #pragma unroll
      for (int r=0;r<4;++r) pr[r] = __expf(acc[r]*0.125f + bias32);
    } else {
      #pragma unroll
      for (int r=0;r<4;++r){
        int n = (r0 + l15) - (c0 + (l4<<2) + r);
        n = n<0 ? 0 : (n>32 ? 32 : n);
        pr[r] = __expf(acc[r]*0.125f + biasl[n]);
      }
    }
    float p0 = m4v.x*pr[0], p1 = m4v.y*pr[1], p2 = m4v.z*pr[2], p3 = m4v.w*pr[3];
    rs += (p0+p1)+(p2+p3);
    // p -> LDS [qrow=l15][kp], swizzled 16B chunks, one b64 write
    int byte = (c0 + (l4<<2)) << 1;
    int ch = (byte>>4) ^ l15;
    uint2 pk; pk.x = pack2(p0,p1); pk.y = pack2(p2,p3);
    *(uint2*)(sm + l15*4096 + (ch<<4) + (byte&15)) = pk;
  }

  // ---- row-sum: reduce over l4 groups (2 shfl), then over 8 waves ----
  {
    rs += __shfl_xor(rs, 16);
    rs += __shfl_xor(rs, 32);
    float* wsum = (float*)(sm+WSUM_OFF_L);
    if (l < 16) wsum[(w<<4) + l15] = rs;
  }
  BAR();
  if (tid < 16){
    float* wsum = (float*)(sm+WSUM_OFF_L);
    float t2 = 0.f;
    #pragma unroll
    for (int i=0;i<8;++i) t2 += wsum[(i<<4) + tid];
    ((float*)(sm+RECIP_OFF_L))[tid] = 1.f/t2;
  }
  BAR();
  const float* recip = (const float*)(sm+RECIP_OFF_L);
  float* attb = (float*)(attn_out + (size_t)bh*SS*SS + (size_t)r0*SS);

  // stream one full 8KB attn row: 8 hoisted LDS reads -> 8 independent
  // back-to-back nt stores at consecutive addresses.
  auto stream_row = [&](int row){
    float rc = recip[row];
    float* dst = attb + (size_t)row*SS;
    uint2 pk[8];
    #pragma unroll
    for (int c=0;c<8;++c){
      int byte = (c<<9) + (l<<3);               // bf16 byte offset in row
      int ch = (byte>>4) ^ row;
      pk[c] = *(const uint2*)(sm + row*4096 + (ch<<4) + (byte&15));
    }
    #pragma unroll
    for (int c=0;c<8;++c){
      short s0 = (short)(pk[c].x & 0xffff), s1 = (short)(pk[c].x >> 16);
      short s2 = (short)(pk[c].y & 0xffff), s3 = (short)(pk[c].y >> 16);
      f32x4 o = (f32x4){ b2f(s0)*rc, b2f(s1)*rc, b2f(s2)*rc, b2f(s3)*rc };
      __builtin_nontemporal_store(o, (f32x4*)(dst + (c<<8) + (l<<2)));
    }
  };

  if (w < 4){
    // ---- PV (waves 0-3): dv-stripe w*16, FULL k range, oh direct ----
    f32x4 acco = (f32x4){0.f,0.f,0.f,0.f};
    int dbase = w<<4;
    const char* vr = vtb + (size_t)(dbase + l15)*4096 + (l4<<4);
    #pragma unroll 4
    for (int kt=0; kt<64; ++kt){
      int ch = ((kt<<2) + l4) ^ l15;            // p chunk idx ^ row swizzle
      bfrag af = *(const bfrag*)(sm + l15*4096 + (ch<<4));
      bfrag bv = *(const bfrag*)(vr + (kt<<6));
      acco = MFMA16(af, bv, acco);
    }
    short* oh = (short*)(ws + OH_OFF);
    #pragma unroll
    for (int r=0;r<4;++r){
      int rowl = (l4<<2) + r;
      float rc = recip[rowl];
      size_t sg = (size_t)b*SS + (qblk<<4) + rowl;
      oh[sg*512 + h*64 + dbase + l15] = f2bs(acco[r]*rc);
    }
    stream_row(12 + w);                          // PV waves take 1 row each
  } else {
    int sw = w - 4;
    stream_row(sw);                              // stream waves: 3 rows each
    stream_row(sw + 4);
    stream_row(sw + 8);
  }
}

// ------------------------- launch -----------------------------------------
extern "C" void kernel_launch(void* const* d_in, const int* in_sizes, int n_in,
                              void* d_out, int out_size, void* d_ws, size_t ws_size,
                              hipStream_t stream){
  const float* q   = (const float*)d_in[0];
  const float* k   = (const float*)d_in[1];
  const float* v   = (const float*)d_in[2];
  const int*  mask = (const int*)  d_in[3];
  const float* Wq  = (const float*)d_in[4];
  const float* Wk  = (const float*)d_in[5];
  const float* Wv  = (const float*)d_in[6];
  const float* Wfc = (const float*)d_in[7];
  const float* rb  = (const float*)d_in[8];
  char* ws = (char*)d_ws;
  float* out  = (float*)d_out;
  float* attn = out + (size_t)BB*SS*512;

  (void)hipFuncSetAttribute((const void*)attn_k,
        hipFuncAttributeMaxDynamicSharedMemorySize, LDS_TOTAL);

  conv_w_k<<<dim3(128,1,4), 256, 0, stream>>>(Wq, Wk, Wv, Wfc, ws);
  conv_x_k<<<dim3(2048,1,3), 256, 0, stream>>>(q, k, v, ws);
  gemm_proj_k<<<dim3(256,1,3), 256, 0, stream>>>(ws);
  attn_k<<<dim3(32,128), 512, LDS_TOTAL, stream>>>(ws, mask, rb, attn);
  gemm_final_k<<<dim3(256,1,1), 256, 0, stream>>>(ws, out);
}